// Round 10
// baseline (140.028 us; speedup 1.0000x reference)
//
#include <hip/hip_runtime.h>

#define N_NODES 8192
#define DIM     128
#define N_COMM  100
#define MARGIN  1.0f
#define NTILES  2080              // 64*65/2 triangular tiles
#define MP_STR  66                // min-partial stride (65 slots + pad)

// TWO-KERNEL structure (round-10): prep is gone. minneg self-converts its
// tiles (x fp32 -> bf16 in staging), computes sq from staged bf16 in LDS,
// and writes min-neg PARTIALS (plain stores, no init needed): for node n in
// row-block nb, row-role tiles (nb,by) write slot by (0..nb), col-role tiles
// (bx,nb) write slot bx+1 (nb+1..64) -> slots 0..64 each written exactly once.
// pos (1 block/community) compacts members from comm, reduces the 65 partials
// to mn, and runs the wave-per-tile-pair MFMA loop with in-register cvt.
// (R5: grid.sync >>100us. R8: row-major direct loads L2-request-bound.
//  Launch overhead ~8us/launch -> 3->2 launches is the win here.)
#define KH       64
#define LDS_STRM 72
#define RP_STR   68               // row-min partial stride (floats)

typedef __attribute__((ext_vector_type(8)))  short bf16x8;
typedef __attribute__((ext_vector_type(16))) float f32x16;

__device__ inline unsigned short f32_to_bf16_rne(float f) {
    unsigned u = __float_as_uint(f);
    unsigned r = u + 0x7fffu + ((u >> 16) & 1u);
    return (unsigned short)(r >> 16);
}
__device__ inline float bf16u_to_f32(unsigned short h) {
    return __uint_as_float(((unsigned)h) << 16);
}
__device__ inline unsigned pack2_bf16(float a, float b) {
    return (unsigned)f32_to_bf16_rne(a) | ((unsigned)f32_to_bf16_rne(b) << 16);
}

// ---------------------------------------------------------------------------
// Kernel 1: MFMA X·X^T (plain bf16, self-converted), triangular grid (2080
// blocks), K staged in 64-halves. Row-min and col-min written as PARTIALS.
// C/D layout (m74/m101): col = lane&31, row = (reg&3) + 8*(reg>>2) + 4*(lane>>5).
__global__ __launch_bounds__(256, 4)
void minneg_mfma_kernel(const float* __restrict__ x,
                        const int* __restrict__ comm,
                        float* __restrict__ part,
                        unsigned int* __restrict__ done) {
    __shared__ __align__(16) unsigned short lds[2][128][LDS_STRM];  // 36864 B
    __shared__ __align__(16) float sqlds[256];                      //  1024 B

    if (blockIdx.x == 0 && threadIdx.x == 0) atomicExch(done, 0u);

    // linear -> lower-triangle (bx >= by)
    const int b = blockIdx.x;
    int bx = (int)((sqrtf(8.f * (float)b + 1.f) - 1.f) * 0.5f);
    while ((bx + 1) * (bx + 2) / 2 <= b) ++bx;
    while (bx * (bx + 1) / 2 > b) --bx;
    const int by = b - bx * (bx + 1) / 2;

    const int tid  = threadIdx.x;
    const int lane = tid & 63;
    const int w    = tid >> 6;
    const int wr   = w >> 1, wc = w & 1;
    const int lr   = lane & 31;
    const int lh   = lane >> 5;
    const int i0   = bx * 128;      // A rows
    const int j0   = by * 128;      // B rows (= output cols)

    f32x16 acc[2][2];
    #pragma unroll
    for (int g = 0; g < 2; ++g)
        #pragma unroll
        for (int h = 0; h < 2; ++h)
            #pragma unroll
            for (int e = 0; e < 16; ++e) acc[g][h][e] = 0.f;

    for (int kh = 0; kh < 2; ++kh) {
        __syncthreads();    // previous compute done reading LDS
        // stage+convert 2 tiles x 128 rows x 64 k: fp32 -> bf16, 8/thread
        #pragma unroll
        for (int it = 0; it < 8; ++it) {
            int g    = tid + it * 256;          // 0..2047
            int tile = g >> 10;                 // 0..1
            int row  = (g >> 3) & 127;
            int seg  = g & 7;
            int rbase = tile ? j0 : i0;
            const float* src = &x[(size_t)(rbase + row) * DIM + kh * KH + seg * 8];
            float4 v0 = *(const float4*)src;
            float4 v1 = *(const float4*)(src + 4);
            uint4 o;
            o.x = pack2_bf16(v0.x, v0.y);
            o.y = pack2_bf16(v0.z, v0.w);
            o.z = pack2_bf16(v1.x, v1.y);
            o.w = pack2_bf16(v1.z, v1.w);
            *(uint4*)&lds[tile][row][seg * 8] = o;
        }
        __syncthreads();

        // sq pass: thread t sums squares of row t's 64 staged bf16 (ascending k)
        {
            int tile = tid >> 7, row = tid & 127;
            float s = 0.f;
            #pragma unroll
            for (int i = 0; i < 32; ++i) {
                unsigned uu = *(const unsigned*)&lds[tile][row][2 * i];
                float a = bf16u_to_f32((unsigned short)(uu & 0xffffu));
                float c2 = bf16u_to_f32((unsigned short)(uu >> 16));
                s += a * a;
                s += c2 * c2;
            }
            if (kh == 0) sqlds[tid] = s; else sqlds[tid] += s;
        }

        #pragma unroll
        for (int ks = 0; ks < 4; ++ks) {
            const int kb = ks * 16 + lh * 8;
            bf16x8 a[2], bb[2];
            #pragma unroll
            for (int g = 0; g < 2; ++g)
                a[g] = *(const bf16x8*)&lds[0][wr * 64 + g * 32 + lr][kb];
            #pragma unroll
            for (int h = 0; h < 2; ++h)
                bb[h] = *(const bf16x8*)&lds[1][wc * 64 + h * 32 + lr][kb];
            #pragma unroll
            for (int g = 0; g < 2; ++g)
                #pragma unroll
                for (int h = 0; h < 2; ++h)
                    acc[g][h] = __builtin_amdgcn_mfma_f32_32x32x16_bf16(
                        a[g], bb[h], acc[g][h], 0, 0, 0);
        }
    }

    // ---- epilogue: d2 = sq_i + sq_j - 2*dot ; col-min AND row-min over negatives.
    __syncthreads();    // staging dead (overlays) + sqlds complete for all rows
    float (*rowpart)[RP_STR] = (float (*)[RP_STR])lds;                    // 34816 B
    float (*colpart)[2]      = (float (*)[2])((char*)lds + 128 * RP_STR * 4);  // 1 KB

    const float FINF = __uint_as_float(0x7f800000u);
    float cminh[2] = {FINF, FINF};

    #pragma unroll
    for (int g = 0; g < 2; ++g) {
        float rmin[16];
        #pragma unroll
        for (int e = 0; e < 16; ++e) rmin[e] = FINF;

        #pragma unroll
        for (int h = 0; h < 2; ++h) {
            int colt = wc * 64 + h * 32 + lr;
            int j  = j0 + colt;
            int cj = comm[j];
            float sqj = sqlds[128 + colt];
            float cm = FINF;
            #pragma unroll
            for (int q = 0; q < 4; ++q) {
                int rbl = wr * 64 + g * 32 + 4 * lh + 8 * q;   // local A row
                int4   civ = *(const int4*)&comm[i0 + rbl];
                float4 sqv = *(const float4*)&sqlds[rbl];
                const int cvals[4] = {civ.x, civ.y, civ.z, civ.w};
                const float svals[4] = {sqv.x, sqv.y, sqv.z, sqv.w};
                #pragma unroll
                for (int t = 0; t < 4; ++t) {
                    float d2 = fmaxf(svals[t] + sqj - 2.f * acc[g][h][q * 4 + t], 0.f);
                    if (cvals[t] != cj) {
                        cm = fminf(cm, d2);
                        rmin[q * 4 + t] = fminf(rmin[q * 4 + t], d2);
                    }
                }
            }
            cminh[h] = fminf(cminh[h], cm);
        }

        // write this g's row-min partials; acc[g] now dead
        #pragma unroll
        for (int q = 0; q < 4; ++q)
            #pragma unroll
            for (int t = 0; t < 4; ++t) {
                int rowl = wr * 64 + g * 32 + 4 * lh + 8 * q + t;
                rowpart[rowl][wc * 32 + lr] = rmin[q * 4 + t];
            }
    }

    #pragma unroll
    for (int h = 0; h < 2; ++h)
        cminh[h] = fminf(cminh[h], __shfl_xor(cminh[h], 32));
    if (lh == 0) {
        #pragma unroll
        for (int h = 0; h < 2; ++h)
            colpart[wc * 64 + h * 32 + lr][wr] = cminh[h];
    }
    __syncthreads();
    if (tid < 128) {
        float m = FINF;
        #pragma unroll
        for (int k = 0; k < 16; ++k) {
            float4 vv = *(const float4*)&rowpart[tid][k * 4];
            m = fminf(m, fminf(fminf(vv.x, vv.y), fminf(vv.z, vv.w)));
        }
        float cm = fminf(colpart[tid][0], colpart[tid][1]);
        // partial slots: row role -> by (0..bx), col role -> bx+1 (by+1..64)
        part[(size_t)(i0 + tid) * MP_STR + by]     = m;
        part[(size_t)(j0 + tid) * MP_STR + bx + 1] = cm;
    }
}

// ---------------------------------------------------------------------------
// Kernel 2: positives, one block per community. Stable ballot-compaction of
// members, local sq (bf16-based, same chain as minneg) + mn from 65 partials,
// wave-per-32x32-tile-pair MFMA with in-register fp32->bf16 conversion,
// and done-counter finalize (last of 100 blocks reduces -> out).
__global__ __launch_bounds__(256)
void pos_kernel(const float* __restrict__ x,
                const int* __restrict__ comm,
                const float* __restrict__ part,
                double* __restrict__ psum,
                unsigned int* __restrict__ pcnt,
                unsigned int* __restrict__ done,
                float* __restrict__ out) {
    __shared__ int   mem[256];
    __shared__ float sqA[256];
    __shared__ float mnA[256];
    __shared__ int   ssize;
    __shared__ double       sred[4];
    __shared__ unsigned int cred[4];
    __shared__ unsigned int lastflag;

    const int c    = blockIdx.x;
    const int tid  = threadIdx.x;
    const int lane = tid & 63;
    const int w    = tid >> 6;
    const int lr   = lane & 31;
    const int lh   = lane >> 5;
    const float FINF = __uint_as_float(0x7f800000u);

    // ---- stable member compaction (wave 0)
    if (w == 0) {
        int base = 0;
        for (int ib = 0; ib < N_NODES; ib += 64) {
            bool mt = (comm[ib + lane] == c);
            unsigned long long mask = __ballot(mt);
            int pre = __popcll(mask & ((1ull << lane) - 1ull));
            if (mt && base + pre < 256) mem[base + pre] = ib + lane;
            base += __popcll(mask);
        }
        if (lane == 0) ssize = (base < 256) ? base : 256;
    }
    __syncthreads();
    const int size = ssize;

    // ---- per-member sq (bf16 of x, (sum k<64) + (sum k>=64), ascending) + mn
    if (tid < size) {
        int n = mem[tid];
        const float* px = x + (size_t)n * DIM;
        float slo = 0.f, shi = 0.f;
        #pragma unroll
        for (int jj = 0; jj < 16; ++jj) {
            float4 v = *(const float4*)&px[jj * 4];
            float a0 = bf16u_to_f32(f32_to_bf16_rne(v.x));
            float a1 = bf16u_to_f32(f32_to_bf16_rne(v.y));
            float a2 = bf16u_to_f32(f32_to_bf16_rne(v.z));
            float a3 = bf16u_to_f32(f32_to_bf16_rne(v.w));
            slo += a0 * a0; slo += a1 * a1; slo += a2 * a2; slo += a3 * a3;
        }
        #pragma unroll
        for (int jj = 16; jj < 32; ++jj) {
            float4 v = *(const float4*)&px[jj * 4];
            float a0 = bf16u_to_f32(f32_to_bf16_rne(v.x));
            float a1 = bf16u_to_f32(f32_to_bf16_rne(v.y));
            float a2 = bf16u_to_f32(f32_to_bf16_rne(v.z));
            float a3 = bf16u_to_f32(f32_to_bf16_rne(v.w));
            shi += a0 * a0; shi += a1 * a1; shi += a2 * a2; shi += a3 * a3;
        }
        sqA[tid] = slo + shi;
        float m2 = FINF;
        const float* pp = part + (size_t)n * MP_STR;
        #pragma unroll 5
        for (int p = 0; p < 65; ++p) m2 = fminf(m2, pp[p]);
        mnA[tid] = (m2 == FINF) ? -1.f : sqrtf(fmaxf(m2, 0.f));
    }
    __syncthreads();

    // ---- tile-pair MFMA loop
    float tsum = 0.f;
    unsigned int tcnt = 0u;
    if (size > 0) {
        const int m = (size + 31) >> 5;
        for (int idx = w; idx < m * m; idx += 4) {
            int ti = idx / m, tj = idx - ti * m;
            int s0 = ti * 32, t0 = tj * 32;
            int slotA = s0 + lr, slotB = t0 + lr;
            int nodeA = mem[slotA < size ? slotA : size - 1];
            int nodeB = mem[slotB < size ? slotB : size - 1];
            const float* pA = x + (size_t)nodeA * DIM + lh * 8;
            const float* pB = x + (size_t)nodeB * DIM + lh * 8;

            f32x16 a0;
            #pragma unroll
            for (int e = 0; e < 16; ++e) a0[e] = 0.f;

            #pragma unroll
            for (int ks = 0; ks < 8; ++ks) {
                const float* qa = pA + ks * 16;
                const float* qb = pB + ks * 16;
                float4 va0 = *(const float4*)qa;
                float4 va1 = *(const float4*)(qa + 4);
                float4 vb0 = *(const float4*)qb;
                float4 vb1 = *(const float4*)(qb + 4);
                uint4 ua, ub;
                ua.x = pack2_bf16(va0.x, va0.y); ua.y = pack2_bf16(va0.z, va0.w);
                ua.z = pack2_bf16(va1.x, va1.y); ua.w = pack2_bf16(va1.z, va1.w);
                ub.x = pack2_bf16(vb0.x, vb0.y); ub.y = pack2_bf16(vb0.z, vb0.w);
                ub.z = pack2_bf16(vb1.x, vb1.y); ub.w = pack2_bf16(vb1.z, vb1.w);
                bf16x8 av = __builtin_bit_cast(bf16x8, ua);
                bf16x8 bv = __builtin_bit_cast(bf16x8, ub);
                a0 = __builtin_amdgcn_mfma_f32_32x32x16_bf16(av, bv, a0, 0, 0, 0);
            }

            float sqb = sqA[slotB < size ? slotB : size - 1];
            #pragma unroll
            for (int q = 0; q < 4; ++q)
                #pragma unroll
                for (int t = 0; t < 4; ++t) {
                    int r = 4 * lh + 8 * q + t;          // output row within tile
                    int e = q * 4 + t;
                    if ((s0 + r < size) && (slotB < size) && (s0 + r != slotB)) {
                        float mn = mnA[s0 + r];
                        if (mn >= 0.f) {
                            float d2   = sqA[s0 + r] + sqb - 2.f * a0[e];
                            float dist = sqrtf(fmaxf(d2, 0.f));
                            tsum += fmaxf(dist - mn + MARGIN, 0.f);
                            tcnt += 1u;
                        }
                    }
                }
        }
    }

    #pragma unroll
    for (int off = 32; off > 0; off >>= 1) {
        tsum += __shfl_down(tsum, off);
        tcnt += __shfl_down(tcnt, off);
    }
    if (lane == 0) { sred[w] = (double)tsum; cred[w] = tcnt; }
    __syncthreads();
    if (tid == 0) {
        double s = sred[0] + sred[1] + sred[2] + sred[3];
        unsigned int cc = cred[0] + cred[1] + cred[2] + cred[3];
        atomicExch((unsigned long long*)&psum[c],
                   (unsigned long long)__double_as_longlong(s));
        atomicExch(&pcnt[c], cc);
        __threadfence();
        unsigned r = atomicAdd(done, 1u);
        lastflag = (r == N_COMM - 1u) ? 1u : 0u;
    }
    __syncthreads();

    // ---- last-block finalize
    if (lastflag) {
        double s = 0.0; unsigned int cc = 0u;
        for (int b2 = tid; b2 < N_COMM; b2 += 256) {
            unsigned long long uv =
                atomicAdd((unsigned long long*)&psum[b2], 0ull);   // coherent reads
            s  += __longlong_as_double((long long)uv);
            cc += atomicAdd(&pcnt[b2], 0u);
        }
        #pragma unroll
        for (int off = 32; off > 0; off >>= 1) {
            s  += __shfl_down(s, off);
            cc += __shfl_down(cc, off);
        }
        if (lane == 0) { sred[w] = s; cred[w] = cc; }
        __syncthreads();
        if (tid == 0) {
            double st = sred[0] + sred[1] + sred[2] + sred[3];
            unsigned int ct = cred[0] + cred[1] + cred[2] + cred[3];
            out[0] = (ct > 0u) ? (float)(st / (double)ct) : 0.f;
        }
    }
}

// ---------------------------------------------------------------------------
extern "C" void kernel_launch(void* const* d_in, const int* in_sizes, int n_in,
                              void* d_out, int out_size, void* d_ws, size_t ws_size,
                              hipStream_t stream) {
    const float* x    = (const float*)d_in[0];
    const int*   comm = (const int*)d_in[1];
    float*       out  = (float*)d_out;

    // workspace layout (bytes):
    //      0 uint   done[1]                 512 (padded)
    //    512 double psum[100]              1024 (padded)
    //   1536 uint   pcnt[100]               512 (padded)
    //   2048 float  part[8192*66]       2162688   (total ~2.2 MB)
    char* ws = (char*)d_ws;
    unsigned int* done = (unsigned int*)(ws);
    double*       psum = (double*)(ws + 512);
    unsigned int* pcnt = (unsigned int*)(ws + 1536);
    float*        part = (float*)(ws + 2048);

    minneg_mfma_kernel<<<NTILES, 256, 0, stream>>>(x, comm, part, done);

    pos_kernel<<<N_COMM, 256, 0, stream>>>(x, comm, part, psum, pcnt, done, out);
}

// Round 11
// 108.704 us; speedup vs baseline: 1.2882x; 1.2882x over previous
//
#include <hip/hip_runtime.h>

#define N_NODES 8192
#define DIM     128
#define N_COMM  100
#define MARGIN  1.0f
#define NPOSBLK (N_COMM * 4)

// Single-bf16 Gram (round-7 configuration — best measured: 108.5 us).
// minneg: 128x128 tile, 4 waves of 64x64, mfma 32x32x16 bf16, K staged in
// 64-wide halves. LDS = 2 tiles x 128 x 72 shorts = 36864 B -> 4 blocks/CU.
// Structure record: R5 cooperative grid.sync = 597us (per-XCD L2 non-coherent
// sync spin); R8 direct-global row-major = L2-request-bound (+22us); R9
// fragment-order = parity; R10 2-kernel (100-block pos) = serial-latency
// disaster (+30us). 3-launch + done-counter pos/finalize merge is optimal.
#define KH       64
#define LDS_STRM 72
#define RP_STR   68               // row-min partial stride (floats)

typedef __attribute__((ext_vector_type(8)))  short bf16x8;
typedef __attribute__((ext_vector_type(16))) float f32x16;

__device__ inline unsigned short f32_to_bf16_rne(float f) {
    unsigned u = __float_as_uint(f);
    unsigned r = u + 0x7fffu + ((u >> 16) & 1u);
    return (unsigned short)(r >> 16);
}

// ---------------------------------------------------------------------------
// Kernel 0 (merged): blocks 0..2047 = bf16 convert + row sq norms + min_d2
// init (wave per row); block 2048 = community bucketing + counter zeroing.
__global__ __launch_bounds__(256)
void prep_kernel(const float* __restrict__ x,
                 const int* __restrict__ comm,
                 unsigned short* __restrict__ xh,
                 float* __restrict__ sq,
                 unsigned int* __restrict__ min_d2,
                 int* __restrict__ offs,
                 int* __restrict__ members,
                 double* __restrict__ psum,
                 unsigned int* __restrict__ pcnt,
                 unsigned int* __restrict__ done) {
    __shared__ int scnt[N_COMM];
    __shared__ int scur[N_COMM];
    const int tid = threadIdx.x;

    if (blockIdx.x < 2048) {
        int row  = blockIdx.x * 4 + (tid >> 6);
        int lane = tid & 63;
        const float* p = x + (size_t)row * DIM;
        float v0 = p[lane], v1 = p[lane + 64];
        unsigned short h0 = f32_to_bf16_rne(v0), h1 = f32_to_bf16_rne(v1);
        size_t base = (size_t)row * DIM;
        xh[base + lane] = h0;  xh[base + 64 + lane] = h1;
        float s = v0 * v0 + v1 * v1;   // sq stays fp32-exact
        #pragma unroll
        for (int off = 32; off > 0; off >>= 1) s += __shfl_down(s, off);
        if (lane == 0) {
            sq[row] = s;
            min_d2[row] = 0x7f800000u;   // +inf bits
        }
        return;
    }

    // ---- bucketing block
    if (tid < N_COMM) {
        scnt[tid] = 0;
        psum[tid] = 0.0;      // pos kernel accumulates -> zero each launch
        pcnt[tid] = 0u;
    }
    if (tid == 0) *done = 0u;
    __syncthreads();
    for (int i = tid; i < N_NODES; i += 256) atomicAdd(&scnt[comm[i]], 1);
    __syncthreads();
    if (tid == 0) {
        int acc = 0;
        for (int c = 0; c < N_COMM; ++c) { scur[c] = acc; offs[c] = acc; acc += scnt[c]; }
        offs[N_COMM] = acc;
    }
    __syncthreads();
    for (int i = tid; i < N_NODES; i += 256) {
        int p = atomicAdd(&scur[comm[i]], 1);
        members[p] = i;
    }
}

// ---------------------------------------------------------------------------
// Kernel 1: MFMA X·X^T (plain bf16), exact triangular grid (2080 blocks),
// K staged in 64-halves (36864 B LDS -> 4 blocks/CU), col-min AND row-min.
// C/D layout (m74/m101): col = lane&31, row = (reg&3) + 8*(reg>>2) + 4*(lane>>5).
__global__ __launch_bounds__(256, 4)
void minneg_mfma_kernel(const unsigned short* __restrict__ xh,
                        const int* __restrict__ comm,
                        const float* __restrict__ sq,
                        unsigned int* __restrict__ min_d2) {
    __shared__ __align__(16) unsigned short lds[2][128][LDS_STRM];  // 36864 B

    // linear -> lower-triangle (bx >= by)
    const int b = blockIdx.x;
    int bx = (int)((sqrtf(8.f * (float)b + 1.f) - 1.f) * 0.5f);
    while ((bx + 1) * (bx + 2) / 2 <= b) ++bx;
    while (bx * (bx + 1) / 2 > b) --bx;
    const int by = b - bx * (bx + 1) / 2;

    const int tid  = threadIdx.x;
    const int lane = tid & 63;
    const int w    = tid >> 6;
    const int wr   = w >> 1, wc = w & 1;
    const int lr   = lane & 31;
    const int lh   = lane >> 5;
    const int i0   = bx * 128;      // A rows
    const int j0   = by * 128;      // B rows (= output cols)

    f32x16 acc[2][2];
    #pragma unroll
    for (int g = 0; g < 2; ++g)
        #pragma unroll
        for (int h = 0; h < 2; ++h)
            #pragma unroll
            for (int e = 0; e < 16; ++e) acc[g][h][e] = 0.f;

    for (int kh = 0; kh < 2; ++kh) {
        __syncthreads();    // previous compute done reading LDS
        // stage 2 tiles x 128 rows x 64 bf16: 2048 16B-chunks, 8 per thread
        #pragma unroll
        for (int it = 0; it < 8; ++it) {
            int g    = tid + it * 256;          // 0..2047
            int tile = g >> 10;                 // 0..1
            int row  = (g >> 3) & 127;
            int seg  = g & 7;
            int rbase = tile ? j0 : i0;
            uint4 v = *(const uint4*)&xh[(size_t)(rbase + row) * DIM + kh * KH + seg * 8];
            *(uint4*)&lds[tile][row][seg * 8] = v;
        }
        __syncthreads();

        #pragma unroll
        for (int ks = 0; ks < 4; ++ks) {
            const int kb = ks * 16 + lh * 8;
            bf16x8 a[2], bb[2];
            #pragma unroll
            for (int g = 0; g < 2; ++g)
                a[g] = *(const bf16x8*)&lds[0][wr * 64 + g * 32 + lr][kb];
            #pragma unroll
            for (int h = 0; h < 2; ++h)
                bb[h] = *(const bf16x8*)&lds[1][wc * 64 + h * 32 + lr][kb];
            #pragma unroll
            for (int g = 0; g < 2; ++g)
                #pragma unroll
                for (int h = 0; h < 2; ++h)
                    acc[g][h] = __builtin_amdgcn_mfma_f32_32x32x16_bf16(
                        a[g], bb[h], acc[g][h], 0, 0, 0);
        }
    }

    // ---- epilogue: d2 = sq_i + sq_j - 2*dot ; col-min AND row-min over negatives.
    __syncthreads();    // staging LDS dead -> reuse as reduction overlays
    float (*rowpart)[RP_STR] = (float (*)[RP_STR])lds;                    // 34816 B
    float (*colpart)[2]      = (float (*)[2])((char*)lds + 128 * RP_STR * 4);  // 1 KB

    const float FINF = __uint_as_float(0x7f800000u);
    float cminh[2] = {FINF, FINF};

    #pragma unroll
    for (int g = 0; g < 2; ++g) {
        float rmin[16];
        #pragma unroll
        for (int e = 0; e < 16; ++e) rmin[e] = FINF;

        #pragma unroll
        for (int h = 0; h < 2; ++h) {
            int colt = wc * 64 + h * 32 + lr;
            int j  = j0 + colt;
            int cj = comm[j];
            float sqj = sq[j];
            float cm = FINF;
            #pragma unroll
            for (int q = 0; q < 4; ++q) {
                int rb = i0 + wr * 64 + g * 32 + 4 * lh + 8 * q;
                int4   civ = *(const int4*)&comm[rb];
                float4 sqv = *(const float4*)&sq[rb];
                const int cvals[4] = {civ.x, civ.y, civ.z, civ.w};
                const float svals[4] = {sqv.x, sqv.y, sqv.z, sqv.w};
                #pragma unroll
                for (int t = 0; t < 4; ++t) {
                    float d2 = fmaxf(svals[t] + sqj - 2.f * acc[g][h][q * 4 + t], 0.f);
                    if (cvals[t] != cj) {
                        cm = fminf(cm, d2);
                        rmin[q * 4 + t] = fminf(rmin[q * 4 + t], d2);
                    }
                }
            }
            cminh[h] = fminf(cminh[h], cm);
        }

        // write this g's row-min partials; acc[g] now dead
        #pragma unroll
        for (int q = 0; q < 4; ++q)
            #pragma unroll
            for (int t = 0; t < 4; ++t) {
                int rowl = wr * 64 + g * 32 + 4 * lh + 8 * q + t;
                rowpart[rowl][wc * 32 + lr] = rmin[q * 4 + t];
            }
    }

    #pragma unroll
    for (int h = 0; h < 2; ++h)
        cminh[h] = fminf(cminh[h], __shfl_xor(cminh[h], 32));
    if (lh == 0) {
        #pragma unroll
        for (int h = 0; h < 2; ++h)
            colpart[wc * 64 + h * 32 + lr][wr] = cminh[h];
    }
    __syncthreads();
    if (tid < 128) {
        float m = FINF;
        #pragma unroll
        for (int k = 0; k < 16; ++k) {
            float4 vv = *(const float4*)&rowpart[tid][k * 4];
            m = fminf(m, fminf(fminf(vv.x, vv.y), fminf(vv.z, vv.w)));
        }
        float cm = fminf(colpart[tid][0], colpart[tid][1]);
        atomicMin(&min_d2[i0 + tid], __float_as_uint(m));
        atomicMin(&min_d2[j0 + tid], __float_as_uint(cm));
    }
}

// ---------------------------------------------------------------------------
// Kernel 2: positives (wave per 32x32 tile-pair, no LDS staging, plain bf16)
// + in-kernel finalize: the LAST pos block (device-scope done-counter)
// reduces the 100 community partials and writes the output.
__global__ __launch_bounds__(256)
void pos_wave_kernel(const unsigned short* __restrict__ xh,
                     const float* __restrict__ sq,
                     const unsigned int* __restrict__ min_d2,
                     const int* __restrict__ offs,
                     const int* __restrict__ members,
                     double* __restrict__ psum,
                     unsigned int* __restrict__ pcnt,
                     unsigned int* __restrict__ done,
                     float* __restrict__ out) {
    __shared__ double       sred[4];
    __shared__ unsigned int cred[4];
    __shared__ unsigned int lastflag;

    const int c    = blockIdx.x >> 2;                     // 4 blocks/community
    const int tid  = threadIdx.x;
    const int lane = tid & 63;
    const int w    = tid >> 6;
    const int lr   = lane & 31;
    const int lh   = lane >> 5;
    const int wsub = ((blockIdx.x & 3) << 2) | w;         // 0..15

    const int beg  = offs[c], end = offs[c + 1];
    const int size = end - beg;

    if (size > 0) {
        const int m = (size + 31) >> 5;                   // 32-row tiles

        float tsum = 0.f;
        unsigned int tcnt = 0u;

        for (int idx = wsub; idx < m * m; idx += 16) {
            int ti = idx / m, tj = idx - ti * m;
            int s0 = ti * 32, t0 = tj * 32;
            int slotA = s0 + lr, slotB = t0 + lr;
            int nodeA = members[beg + (slotA < size ? slotA : size - 1)];
            int nodeB = members[beg + (slotB < size ? slotB : size - 1)];

            // epilogue operands issued early to hide latency under the MFMA loop
            float sqa_own = sq[nodeA];
            unsigned mb = min_d2[nodeA];
            float mn_own = (mb == 0x7f800000u) ? -1.f
                         : sqrtf(fmaxf(__uint_as_float(mb), 0.f));
            float sqb = sq[nodeB];

            const unsigned short* pA = xh + (size_t)nodeA * DIM;
            const unsigned short* pB = xh + (size_t)nodeB * DIM;

            f32x16 a0;
            #pragma unroll
            for (int e = 0; e < 16; ++e) a0[e] = 0.f;

            #pragma unroll
            for (int ks = 0; ks < 8; ++ks) {
                const int ko = ks * 16 + lh * 8;
                bf16x8 av = *(const bf16x8*)&pA[ko];
                bf16x8 bv = *(const bf16x8*)&pB[ko];
                a0 = __builtin_amdgcn_mfma_f32_32x32x16_bf16(av, bv, a0, 0, 0, 0);
            }

            #pragma unroll
            for (int q = 0; q < 4; ++q)
                #pragma unroll
                for (int t = 0; t < 4; ++t) {
                    int r = 4 * lh + 8 * q + t;          // output row within tile
                    float sqa = __shfl(sqa_own, r);      // lane r holds row r's values
                    float mn  = __shfl(mn_own, r);
                    int e = q * 4 + t;
                    if ((s0 + r < size) && (slotB < size) &&
                        (s0 + r != slotB) && (mn >= 0.f)) {
                        float d2   = sqa + sqb - 2.f * a0[e];
                        float dist = sqrtf(fmaxf(d2, 0.f));
                        tsum += fmaxf(dist - mn + MARGIN, 0.f);
                        tcnt += 1u;
                    }
                }
        }

        #pragma unroll
        for (int off = 32; off > 0; off >>= 1) {
            tsum += __shfl_down(tsum, off);
            tcnt += __shfl_down(tcnt, off);
        }
        if (lane == 0 && tcnt > 0u) {
            atomicAdd(&psum[c], (double)tsum);
            atomicAdd(&pcnt[c], tcnt);
        }
    }

    // ---- last-block finalize (device-scope arrival counter)
    __syncthreads();             // all waves' psum/pcnt atomics issued
    if (tid == 0) {
        __threadfence();         // prior atomics visible before done-increment
        unsigned r = atomicAdd(done, 1u);
        lastflag = (r == NPOSBLK - 1u) ? 1u : 0u;
    }
    __syncthreads();
    if (lastflag) {
        double s = 0.0; unsigned int cc = 0u;
        for (int b2 = tid; b2 < N_COMM; b2 += 256) {
            s  += atomicAdd(&psum[b2], 0.0);        // coherent-point reads
            cc += atomicAdd(&pcnt[b2], 0u);
        }
        #pragma unroll
        for (int off = 32; off > 0; off >>= 1) {
            s  += __shfl_down(s, off);
            cc += __shfl_down(cc, off);
        }
        if (lane == 0) { sred[w] = s; cred[w] = cc; }
        __syncthreads();
        if (tid == 0) {
            double st = sred[0] + sred[1] + sred[2] + sred[3];
            unsigned int ct = cred[0] + cred[1] + cred[2] + cred[3];
            out[0] = (ct > 0u) ? (float)(st / (double)ct) : 0.f;
        }
    }
}

// ---------------------------------------------------------------------------
extern "C" void kernel_launch(void* const* d_in, const int* in_sizes, int n_in,
                              void* d_out, int out_size, void* d_ws, size_t ws_size,
                              hipStream_t stream) {
    const float* x    = (const float*)d_in[0];
    const int*   comm = (const int*)d_in[1];
    float*       out  = (float*)d_out;

    // workspace layout (bytes):
    //       0 float  sq[8192]           32768
    //   32768 uint   min_d2[8192]       32768
    //   65536 int    offs[101]            512 (padded)
    //   66048 int    members[8192]      32768
    //   98816 double psum[100]           1024 (padded)
    //   99840 uint   pcnt[100]            512 (padded)
    //  100352 uint   done[1]              512 (padded)
    //  100864 ushort xh[8192*128]     2097152   (total ~2.2 MB)
    char* ws = (char*)d_ws;
    float*          sq      = (float*)(ws);
    unsigned int*   min_d2  = (unsigned int*)(ws + 32768);
    int*            offs    = (int*)(ws + 65536);
    int*            members = (int*)(ws + 66048);
    double*         psum    = (double*)(ws + 98816);
    unsigned int*   pcnt    = (unsigned int*)(ws + 99840);
    unsigned int*   done    = (unsigned int*)(ws + 100352);
    unsigned short* xh      = (unsigned short*)(ws + 100864);

    prep_kernel<<<2049, 256, 0, stream>>>(x, comm, xh, sq, min_d2,
                                          offs, members, psum, pcnt, done);

    const int ntri = (N_NODES / 128) * (N_NODES / 128 + 1) / 2;   // 2080
    minneg_mfma_kernel<<<ntri, 256, 0, stream>>>(xh, comm, sq, min_d2);

    pos_wave_kernel<<<NPOSBLK, 256, 0, stream>>>(xh, sq, min_d2, offs,
                                                 members, psum, pcnt, done, out);
}